// Round 1
// baseline (2597.269 us; speedup 1.0000x reference)
//
#include <hip/hip_runtime.h>
#include <stdint.h>

#define N_USERS 100000
#define N_ITEMS 50000
#define NTOT    150000
#define D       64
#define NNZ     8000000
#define IT      4
#define SCAN_BLK 256
#define CHUNK   (SCAN_BLK*IT)                 /* 1024 */
#define NB      ((NTOT + CHUNK - 1)/CHUNK)    /* 147  */

// ---------------- hop-0 init + zero counters ----------------
__global__ void init_hop0(const float* __restrict__ ue, const float* __restrict__ ie,
                          float* __restrict__ out, int* __restrict__ cnt) {
    int tid = blockIdx.x * blockDim.x + threadIdx.x;
    if (tid < NTOT * (D/4)) {               // one float4 per thread
        int r = tid >> 4;                   // D/4 == 16 float4 per row
        int q = tid & 15;
        const float4* src = (r < N_USERS)
            ? (const float4*)(ue + (size_t)r * D)
            : (const float4*)(ie + (size_t)(r - N_USERS) * D);
        float4 v = src[q];
        ((float4*)(out + (size_t)r * 4 * D))[q] = v;   // slot 0 of [N,4,64]
    }
    if (tid < NTOT) cnt[tid] = 0;
}

// ---------------- row histogram ----------------
__global__ void hist_rows(const int* __restrict__ rows, int* __restrict__ cnt) {
    int e = blockIdx.x * blockDim.x + threadIdx.x;
    if (e < NNZ) atomicAdd(&cnt[rows[e]], 1);
}

// ---------------- 3-phase exclusive scan ----------------
__global__ void scan_p1(const int* __restrict__ cnt, int* __restrict__ partials) {
    __shared__ int sm[SCAN_BLK];
    int t = threadIdx.x, b = blockIdx.x;
    int base = b * CHUNK + t * IT;
    int s = 0;
#pragma unroll
    for (int j = 0; j < IT; ++j) { int i = base + j; s += (i < NTOT) ? cnt[i] : 0; }
    sm[t] = s; __syncthreads();
    for (int off = 1; off < SCAN_BLK; off <<= 1) {
        int x = (t >= off) ? sm[t - off] : 0;
        __syncthreads();
        sm[t] += x;
        __syncthreads();
    }
    if (t == SCAN_BLK - 1) partials[b] = sm[t];
}

__global__ void scan_p2(int* __restrict__ partials) {
    __shared__ int sm[SCAN_BLK];
    int t = threadIdx.x;
    int v = (t < NB) ? partials[t] : 0;
    sm[t] = v; __syncthreads();
    for (int off = 1; off < SCAN_BLK; off <<= 1) {
        int x = (t >= off) ? sm[t - off] : 0;
        __syncthreads();
        sm[t] += x;
        __syncthreads();
    }
    if (t < NB) partials[t] = sm[t] - v;      // exclusive
}

__global__ void scan_p3(const int* __restrict__ partials, int* __restrict__ cnt /* -> cursor */,
                        int* __restrict__ row_ptr) {
    __shared__ int sm[SCAN_BLK];
    int t = threadIdx.x, b = blockIdx.x;
    int base = b * CHUNK + t * IT;
    int c[IT]; int s = 0;
#pragma unroll
    for (int j = 0; j < IT; ++j) { int i = base + j; c[j] = (i < NTOT) ? cnt[i] : 0; s += c[j]; }
    sm[t] = s; __syncthreads();
    for (int off = 1; off < SCAN_BLK; off <<= 1) {
        int x = (t >= off) ? sm[t - off] : 0;
        __syncthreads();
        sm[t] += x;
        __syncthreads();
    }
    int off = partials[b] + sm[t] - s;        // exclusive offset for this thread
#pragma unroll
    for (int j = 0; j < IT; ++j) {
        int i = base + j;
        if (i < NTOT) { row_ptr[i] = off; cnt[i] = off; off += c[j]; }
    }
    if (b == 0 && t == 0) row_ptr[NTOT] = NNZ;
}

// ---------------- scatter edges into CSR order, pack col+keepmask+val ----------------
__global__ void scatter_edges(const int* __restrict__ rows, const int* __restrict__ cols,
                              const float* __restrict__ vals, const float* __restrict__ erand,
                              int* __restrict__ cursor, uint2* __restrict__ edges) {
    int e = blockIdx.x * blockDim.x + threadIdx.x;
    if (e >= NNZ) return;
    int r = rows[e];
    unsigned m = 0;
#pragma unroll
    for (int h = 0; h < 3; ++h) {
        float u = erand[(size_t)h * NNZ + e];
        if (floorf(0.5f + u) != 0.0f) m |= (1u << h);   // exact torch-style keep
    }
    unsigned cm = (unsigned)cols[e] | (m << 18);        // col < 2^18
    float v = vals[e];
    int pos = atomicAdd(&cursor[r], 1);
    edges[pos] = make_uint2(cm, __float_as_uint(v));
}

// ---------------- gather SpMM per hop: one wave per row ----------------
__global__ __launch_bounds__(256) void spmm_hop(const int* __restrict__ row_ptr,
                                                const uint2* __restrict__ edges,
                                                const float* __restrict__ mrand,
                                                float* __restrict__ out, int h) {
    int w    = (blockIdx.x * blockDim.x + threadIdx.x) >> 6;
    int lane = threadIdx.x & 63;
    if (w >= NTOT) return;
    int r = w;
    int start = row_ptr[r], end = row_ptr[r + 1];
    const float* prev = out + (size_t)h * D;   // slot h; index (size_t)c*256 + lane
    float acc = 0.f;
    unsigned hb = 1u << (18 + h);
    for (int e = start; e < end; ++e) {
        uint2 ed = edges[e];
        if (ed.x & hb) {                       // wave-uniform: dropped edges skip gather
            int c = ed.x & 0x3FFFF;
            float wgt = __uint_as_float(ed.y) * 2.0f;
            acc = fmaf(wgt, prev[(size_t)c * 256 + lane], acc);
        }
    }
    float u = mrand[((size_t)h * NTOT + r) * D + lane];
    float res = (u >= 0.1f) ? acc * (1.0f / 0.9f) : 0.0f;
    out[((size_t)r * 4 + (h + 1)) * D + lane] = res;
}

extern "C" void kernel_launch(void* const* d_in, const int* in_sizes, int n_in,
                              void* d_out, int out_size, void* d_ws, size_t ws_size,
                              hipStream_t stream) {
    const float* ue    = (const float*)d_in[0];
    const float* ie    = (const float*)d_in[1];
    const int*   rows  = (const int*)  d_in[2];
    const int*   cols  = (const int*)  d_in[3];
    const float* vals  = (const float*)d_in[4];
    const float* erand = (const float*)d_in[5];
    const float* mrand = (const float*)d_in[6];
    float* out = (float*)d_out;

    // workspace layout (≈65.3 MB)
    char* ws = (char*)d_ws;
    size_t off = 0;
    int* cnt      = (int*)(ws + off); off += (size_t)NTOT * 4;        off = (off + 255) & ~(size_t)255;
    int* row_ptr  = (int*)(ws + off); off += (size_t)(NTOT + 1) * 4;  off = (off + 255) & ~(size_t)255;
    int* partials = (int*)(ws + off); off += (size_t)NB * 4;          off = (off + 255) & ~(size_t)255;
    uint2* edges  = (uint2*)(ws + off); off += (size_t)NNZ * 8;

    init_hop0<<<(NTOT * 16 + 255) / 256, 256, 0, stream>>>(ue, ie, out, cnt);
    hist_rows<<<(NNZ + 255) / 256, 256, 0, stream>>>(rows, cnt);
    scan_p1<<<NB, SCAN_BLK, 0, stream>>>(cnt, partials);
    scan_p2<<<1, SCAN_BLK, 0, stream>>>(partials);
    scan_p3<<<NB, SCAN_BLK, 0, stream>>>(partials, cnt, row_ptr);
    scatter_edges<<<(NNZ + 255) / 256, 256, 0, stream>>>(rows, cols, vals, erand, cnt, edges);
    for (int h = 0; h < 3; ++h) {
        spmm_hop<<<(NTOT * 64 + 255) / 256, 256, 0, stream>>>(row_ptr, edges, mrand, out, h);
    }
}